// Round 1
// baseline (1119.023 us; speedup 1.0000x reference)
//
#include <hip/hip_runtime.h>

#define NSEG 100000
#define DIM 32

// One thread per (row, col) element. Coalesced reads of x; float atomicAdd
// into the per-segment sum table (d_out), one count atomic per row (col==0).
__global__ void scatter_sum_kernel(const float* __restrict__ x,
                                   const int* __restrict__ idx,
                                   float* __restrict__ sums,
                                   float* __restrict__ cnts,
                                   int n_elems) {
    int i = blockIdx.x * blockDim.x + threadIdx.x;
    if (i >= n_elems) return;
    int row = i >> 5;        // DIM = 32
    int col = i & 31;
    int seg = idx[row];
    atomicAdd(&sums[seg * DIM + col], x[i]);
    if (col == 0) {
        atomicAdd(&cnts[seg], 1.0f);
    }
}

__global__ void divide_kernel(float* __restrict__ out,
                              const float* __restrict__ cnts,
                              int n) {
    int i = blockIdx.x * blockDim.x + threadIdx.x;
    if (i >= n) return;
    float c = cnts[i >> 5];
    out[i] = out[i] / fmaxf(c, 1.0f);
}

extern "C" void kernel_launch(void* const* d_in, const int* in_sizes, int n_in,
                              void* d_out, int out_size, void* d_ws, size_t ws_size,
                              hipStream_t stream) {
    const float* x   = (const float*)d_in[0];
    const int*   idx = (const int*)d_in[1];
    float* out  = (float*)d_out;   // segment sums, then means in-place
    float* cnts = (float*)d_ws;    // NSEG floats of scratch

    int n_elems = in_sizes[0];     // 4,000,000 * 32 = 128,000,000

    // Harness poisons d_out / d_ws with 0xAA before every launch — zero them.
    hipMemsetAsync(d_out, 0, (size_t)out_size * sizeof(float), stream);
    hipMemsetAsync(d_ws, 0, (size_t)NSEG * sizeof(float), stream);

    const int threads = 256;
    int blocks = (n_elems + threads - 1) / threads;
    scatter_sum_kernel<<<blocks, threads, 0, stream>>>(x, idx, out, cnts, n_elems);

    int blocks2 = (out_size + threads - 1) / threads;
    divide_kernel<<<blocks2, threads, 0, stream>>>(out, cnts, out_size);
}